// Round 1
// baseline (18157.381 us; speedup 1.0000x reference)
//
#include <hip/hip_runtime.h>
#include <hip/hip_bf16.h>
#include <hip/hip_fp16.h>

// ---------------------------------------------------------------------------
// ModelInstructionAggregate: token-LSTM (batch 8192, T<=16) -> sequential
// instruction-LSTM (8192 steps, batch 1) -> Linear(256->1).
// Round 4: k_seq_lstm only —
//   (a) register-resident weight dots emitted as inline-asm v_dot2_f32_f16
//       with "v" constraints: forces the 192 weight-half2 into ARCH VGPRs
//       (round-3 counters showed VGPR_Count=128 => weights were in AGPRs /
//       scratch, one v_accvgpr_read per fdot2 ~ +1400 VALU cyc/step).
//   (b) pair-mapped gate rows: thread 2u owns rows {i,g} of h-unit u,
//       thread 2u+1 owns {f,o}. Gate exchange via 2x DPP quad-perm lane
//       swap (same wave, no barrier); c kept in registers; h double-
//       buffered f16 in LDS => ONE __syncthreads per step (was 2 + a
//       gates-LDS round trip with 4 waves idle).
// ---------------------------------------------------------------------------

constexpr int H_ = 256;    // hidden
constexpr int T_ = 16;     // max token steps
constexpr int N_ = 8192;   // instructions
constexpr int BI = 16;     // instructions per block in batched kernels

typedef _Float16 half_t;
typedef half_t half2_t __attribute__((ext_vector_type(2)));

#if __has_builtin(__builtin_amdgcn_fdot2)
#define FDOT2(w, h, acc) __builtin_amdgcn_fdot2((w), (h), (acc), false)
#else
__device__ __forceinline__ float fdot2_emul(half2_t w, half2_t h, float acc) {
    return acc + (float)w.x * (float)h.x + (float)w.y * (float)h.y;
}
#define FDOT2(w, h, acc) fdot2_emul((w), (h), (acc))
#endif

// Inline-asm fdot2: "v" constraints pin all operands to ARCH VGPRs so the
// long-lived weight values cannot be allocated to AGPRs (VOP3P has no AGPR
// source path on gfx9xx -> would cost one v_accvgpr_read per use).
__device__ __forceinline__ void fdot2_v(float& acc, half2_t w, half2_t h) {
    asm("v_dot2_f32_f16 %0, %1, %2, %0" : "+v"(acc) : "v"(w), "v"(h));
}

__device__ __forceinline__ float sigmoidf_(float x) {
    return 1.0f / (1.0f + __expf(-x));
}
__device__ __forceinline__ float tanhf_(float x) {
    return 2.0f / (1.0f + __expf(-2.0f * x)) - 1.0f;
}

// lane <-> lane^1 swap via DPP quad_perm {1,0,3,2} (ctrl=0xB1), 1 VALU inst.
__device__ __forceinline__ float dpp_swap1(float x) {
    int xi = __builtin_bit_cast(int, x);
    int r = __builtin_amdgcn_update_dpp(0, xi, 0xB1, 0xF, 0xF, true);
    return __builtin_bit_cast(float, r);
}

// --------------------------- weight transposes -----------------------------
__global__ __launch_bounds__(256) void k_transpose_cat(
    const float* __restrict__ Wih, const float* __restrict__ Whh,
    float4* __restrict__ Wt)
{
    int tid = blockIdx.x * 256 + threadIdx.x;      // 1024 rows * 128 kb
    int kb = tid & 127, row = tid >> 7;
    float4 v = (kb < 64) ? ((const float4*)Wih)[row * 64 + kb]
                         : ((const float4*)Whh)[row * 64 + (kb - 64)];
    Wt[kb * 1024 + row] = v;
}

__global__ __launch_bounds__(256) void k_transpose_i(
    const float* __restrict__ Wsrc, float4* __restrict__ Wt)
{
    int tid = blockIdx.x * 256 + threadIdx.x;      // 1024 rows * 64 kb
    int kb = tid & 63, row = tid >> 6;
    Wt[kb * 1024 + row] = ((const float4*)Wsrc)[row * 64 + kb];
}

// ----------------------- phase 1: batched token LSTM -----------------------
__global__ __launch_bounds__(256, 4) void k_token_lstm(
    const float* __restrict__ tokens, const int* __restrict__ lengths,
    const float4* __restrict__ Wt,   // [128][1024] float4 (x-part then h-part)
    const float* __restrict__ bih, const float* __restrict__ bhh,
    float* __restrict__ embeds)      // [N_][H_]
{
    __shared__ __align__(16) float xs[BI][H_];
    __shared__ __align__(16) float hs[BI][H_];
    __shared__ __align__(16) float cs[BI][H_];
    __shared__ int len[BI];

    const int j = threadIdx.x;
    const int n0 = blockIdx.x * BI;
    if (j < BI) len[j] = lengths[n0 + j];
#pragma unroll
    for (int i = 0; i < BI; ++i) { hs[i][j] = 0.f; cs[i][j] = 0.f; }
    const float b0 = bih[j]       + bhh[j];
    const float b1 = bih[256 + j] + bhh[256 + j];
    const float b2 = bih[512 + j] + bhh[512 + j];
    const float b3 = bih[768 + j] + bhh[768 + j];
    __syncthreads();

    for (int t = 0; t < T_; ++t) {
#pragma unroll
        for (int q = 0; q < 4; ++q) {
            int idx = j + q * 256;
            int i = idx >> 6, e4 = idx & 63;
            ((float4*)xs)[i * 64 + e4] =
                ((const float4*)tokens)[((size_t)(n0 + i) * T_ + t) * 64 + e4];
        }
        __syncthreads();

        float a0[BI], a1[BI], a2[BI], a3[BI];
#pragma unroll
        for (int i = 0; i < BI; ++i) { a0[i] = 0.f; a1[i] = 0.f; a2[i] = 0.f; a3[i] = 0.f; }

        for (int kb = 0; kb < 64; ++kb) {
            float4 w0 = Wt[kb * 1024 + j];
            float4 w1 = Wt[kb * 1024 + 256 + j];
            float4 w2 = Wt[kb * 1024 + 512 + j];
            float4 w3 = Wt[kb * 1024 + 768 + j];
#pragma unroll
            for (int i = 0; i < BI; ++i) {
                float4 x4 = ((const float4*)xs)[i * 64 + kb];
                a0[i] += w0.x * x4.x + w0.y * x4.y + w0.z * x4.z + w0.w * x4.w;
                a1[i] += w1.x * x4.x + w1.y * x4.y + w1.z * x4.z + w1.w * x4.w;
                a2[i] += w2.x * x4.x + w2.y * x4.y + w2.z * x4.z + w2.w * x4.w;
                a3[i] += w3.x * x4.x + w3.y * x4.y + w3.z * x4.z + w3.w * x4.w;
            }
        }
        for (int kb = 0; kb < 64; ++kb) {
            float4 w0 = Wt[(64 + kb) * 1024 + j];
            float4 w1 = Wt[(64 + kb) * 1024 + 256 + j];
            float4 w2 = Wt[(64 + kb) * 1024 + 512 + j];
            float4 w3 = Wt[(64 + kb) * 1024 + 768 + j];
#pragma unroll
            for (int i = 0; i < BI; ++i) {
                float4 h4 = ((const float4*)hs)[i * 64 + kb];
                a0[i] += w0.x * h4.x + w0.y * h4.y + w0.z * h4.z + w0.w * h4.w;
                a1[i] += w1.x * h4.x + w1.y * h4.y + w1.z * h4.z + w1.w * h4.w;
                a2[i] += w2.x * h4.x + w2.y * h4.y + w2.z * h4.z + w2.w * h4.w;
                a3[i] += w3.x * h4.x + w3.y * h4.y + w3.z * h4.z + w3.w * h4.w;
            }
        }
        __syncthreads();

#pragma unroll
        for (int i = 0; i < BI; ++i) {
            if (t < len[i]) {
                float gi = sigmoidf_(a0[i] + b0);
                float gf = sigmoidf_(a1[i] + b1);
                float gg = tanhf_   (a2[i] + b2);
                float go = sigmoidf_(a3[i] + b3);
                float c2 = gf * cs[i][j] + gi * gg;
                cs[i][j] = c2;
                hs[i][j] = go * tanhf_(c2);
            }
        }
    }
#pragma unroll
    for (int i = 0; i < BI; ++i)
        embeds[(size_t)(n0 + i) * H_ + j] = hs[i][j];
}

// --------------------- phase 2a: XI = embeds @ Wih_i^T + b ------------------
__global__ __launch_bounds__(256, 4) void k_xi(
    const float* __restrict__ embeds, const float4* __restrict__ WiT, // [64][1024]
    const float* __restrict__ bih, const float* __restrict__ bhh,
    float* __restrict__ XI)          // [N_][1024]
{
    __shared__ __align__(16) float xs[BI][H_];
    const int j = threadIdx.x;
    const int n0 = blockIdx.x * BI;
#pragma unroll
    for (int q = 0; q < 4; ++q) {
        int idx = j + q * 256;
        int i = idx >> 6, e4 = idx & 63;
        ((float4*)xs)[i * 64 + e4] = ((const float4*)embeds)[(size_t)(n0 + i) * 64 + e4];
    }
    const float b0 = bih[j]       + bhh[j];
    const float b1 = bih[256 + j] + bhh[256 + j];
    const float b2 = bih[512 + j] + bhh[512 + j];
    const float b3 = bih[768 + j] + bhh[768 + j];
    __syncthreads();

    float a0[BI], a1[BI], a2[BI], a3[BI];
#pragma unroll
    for (int i = 0; i < BI; ++i) { a0[i] = 0.f; a1[i] = 0.f; a2[i] = 0.f; a3[i] = 0.f; }

    for (int kb = 0; kb < 64; ++kb) {
        float4 w0 = WiT[kb * 1024 + j];
        float4 w1 = WiT[kb * 1024 + 256 + j];
        float4 w2 = WiT[kb * 1024 + 512 + j];
        float4 w3 = WiT[kb * 1024 + 768 + j];
#pragma unroll
        for (int i = 0; i < BI; ++i) {
            float4 x4 = ((const float4*)xs)[i * 64 + kb];
            a0[i] += w0.x * x4.x + w0.y * x4.y + w0.z * x4.z + w0.w * x4.w;
            a1[i] += w1.x * x4.x + w1.y * x4.y + w1.z * x4.z + w1.w * x4.w;
            a2[i] += w2.x * x4.x + w2.y * x4.y + w2.z * x4.z + w2.w * x4.w;
            a3[i] += w3.x * x4.x + w3.y * x4.y + w3.z * x4.z + w3.w * x4.w;
        }
    }
#pragma unroll
    for (int i = 0; i < BI; ++i) {
        size_t base = (size_t)(n0 + i) * 1024;
        XI[base + j]       = a0[i] + b0;
        XI[base + 256 + j] = a1[i] + b1;
        XI[base + 512 + j] = a2[i] + b2;
        XI[base + 768 + j] = a3[i] + b3;
    }
}

// ----------------- phase 2b: sequential instruction LSTM -------------------
// Single workgroup, 512 threads. Thread pair (2u, 2u+1) owns h-unit u:
//   lane 2u   computes gate rows r0=u       (i) and r1=512+u (g)
//   lane 2u+1 computes gate rows r0=256+u   (f) and r1=768+u (o)
// k 0..191 in ARCH VGPRs (96 half2/row, inline-asm dot2), k 192..255 in LDS
// (uint4, 16 b128 reads/thread/step). Gate exchange = 2 DPP lane swaps.
// c in registers (replicated in the pair); h f16 double-buffered in LDS;
// ONE barrier per step.
constexpr int SMEM_SEQ = 1024 /*hh dbuf*/ + 8 * 1024 * 16 /*wt4*/; // 132096 B

__global__ __launch_bounds__(512, 2)
__attribute__((amdgpu_waves_per_eu(2, 2)))
void k_seq_lstm(
    const float* __restrict__ XI,    // [N_][1024]
    const float* __restrict__ Whh,   // [1024][256]
    float* __restrict__ outs)        // [N_][H_]
{
    extern __shared__ char smem[];
    half2_t* hh  = (half2_t*)smem;               // [2][128] half2 (h dbuf)
    uint4*   wt4 = (uint4*)(smem + 1024);        // [8][1024] k-tail

    const int j = threadIdx.x;
    const int p = j & 1;                 // 0 -> (i,g) rows, 1 -> (f,o) rows
    const int u = j >> 1;                // h-unit 0..255
    const int r0 = p * 256 + u;          // row in [0,512)
    const int r1 = 512 + p * 256 + u;    // row in [512,1024)

    half2_t wa[96], wb[96];
    {
        const float4* w0v = (const float4*)(Whh + (size_t)r0 * H_);
        const float4* w1v = (const float4*)(Whh + (size_t)r1 * H_);
#pragma unroll
        for (int kq = 0; kq < 48; ++kq) {        // k 0..191 -> regs
            float4 v0 = w0v[kq], v1 = w1v[kq];
            wa[2 * kq]     = half2_t{(half_t)v0.x, (half_t)v0.y};
            wa[2 * kq + 1] = half2_t{(half_t)v0.z, (half_t)v0.w};
            wb[2 * kq]     = half2_t{(half_t)v1.x, (half_t)v1.y};
            wb[2 * kq + 1] = half2_t{(half_t)v1.z, (half_t)v1.w};
        }
#pragma unroll
        for (int q = 0; q < 8; ++q) {            // k 192..255 -> LDS uint4
            float4 vA = w0v[48 + 2 * q], vB = w0v[48 + 2 * q + 1];
            uint4 u0;
            u0.x = __builtin_bit_cast(unsigned, half2_t{(half_t)vA.x, (half_t)vA.y});
            u0.y = __builtin_bit_cast(unsigned, half2_t{(half_t)vA.z, (half_t)vA.w});
            u0.z = __builtin_bit_cast(unsigned, half2_t{(half_t)vB.x, (half_t)vB.y});
            u0.w = __builtin_bit_cast(unsigned, half2_t{(half_t)vB.z, (half_t)vB.w});
            wt4[q * 1024 + j] = u0;
            float4 vC = w1v[48 + 2 * q], vD = w1v[48 + 2 * q + 1];
            uint4 u1;
            u1.x = __builtin_bit_cast(unsigned, half2_t{(half_t)vC.x, (half_t)vC.y});
            u1.y = __builtin_bit_cast(unsigned, half2_t{(half_t)vC.z, (half_t)vC.w});
            u1.z = __builtin_bit_cast(unsigned, half2_t{(half_t)vD.x, (half_t)vD.y});
            u1.w = __builtin_bit_cast(unsigned, half2_t{(half_t)vD.z, (half_t)vD.w});
            wt4[q * 1024 + 512 + j] = u1;
        }
    }
    if (j < 128) hh[j] = half2_t{(half_t)0.f, (half_t)0.f};  // h buffer 0 = 0
    __syncthreads();

    float c = 0.f;
    float xi0 = XI[r0], xi1 = XI[r1];
    for (int n = 0; n < N_; ++n) {
        // prefetch next step's XI (last iter re-reads current row; unused)
        const int nn = (n + 1 < N_) ? n + 1 : n;
        const float* pX = XI + (size_t)nn * 1024;
        float nxi0 = pX[r0], nxi1 = pX[r1];

        const float4* hv = (const float4*)(hh + ((n & 1) << 7));
        float acc0 = xi0, acc0b = 0.f, acc1 = xi1, acc1b = 0.f;
#pragma unroll
        for (int kk4 = 0; kk4 < 24; ++kk4) {   // k 0..191 (arch-VGPR weights)
            float4 h4 = hv[kk4];               // wave-uniform LDS broadcast
            half2_t h0 = __builtin_bit_cast(half2_t, h4.x);
            half2_t h1 = __builtin_bit_cast(half2_t, h4.y);
            half2_t h2 = __builtin_bit_cast(half2_t, h4.z);
            half2_t h3 = __builtin_bit_cast(half2_t, h4.w);
            fdot2_v(acc0,  wa[4 * kk4 + 0], h0);
            fdot2_v(acc0b, wa[4 * kk4 + 1], h1);
            fdot2_v(acc0,  wa[4 * kk4 + 2], h2);
            fdot2_v(acc0b, wa[4 * kk4 + 3], h3);
            fdot2_v(acc1,  wb[4 * kk4 + 0], h0);
            fdot2_v(acc1b, wb[4 * kk4 + 1], h1);
            fdot2_v(acc1,  wb[4 * kk4 + 2], h2);
            fdot2_v(acc1b, wb[4 * kk4 + 3], h3);
        }
#pragma unroll
        for (int q = 0; q < 8; ++q) {          // k 192..255 (LDS weights)
            uint4 u0 = wt4[q * 1024 + j];
            uint4 u1 = wt4[q * 1024 + 512 + j];
            float4 h4 = hv[24 + q];
            half2_t h0 = __builtin_bit_cast(half2_t, h4.x);
            half2_t h1 = __builtin_bit_cast(half2_t, h4.y);
            half2_t h2 = __builtin_bit_cast(half2_t, h4.z);
            half2_t h3 = __builtin_bit_cast(half2_t, h4.w);
            acc0  = FDOT2(__builtin_bit_cast(half2_t, u0.x), h0, acc0);
            acc0b = FDOT2(__builtin_bit_cast(half2_t, u0.y), h1, acc0b);
            acc0  = FDOT2(__builtin_bit_cast(half2_t, u0.z), h2, acc0);
            acc0b = FDOT2(__builtin_bit_cast(half2_t, u0.w), h3, acc0b);
            acc1  = FDOT2(__builtin_bit_cast(half2_t, u1.x), h0, acc1);
            acc1b = FDOT2(__builtin_bit_cast(half2_t, u1.y), h1, acc1b);
            acc1  = FDOT2(__builtin_bit_cast(half2_t, u1.z), h2, acc1);
            acc1b = FDOT2(__builtin_bit_cast(half2_t, u1.w), h3, acc1b);
        }
        float a0 = acc0 + acc0b;   // p=0: i-gate,  p=1: f-gate
        float a1 = acc1 + acc1b;   // p=0: g-gate,  p=1: o-gate
        float s0 = dpp_swap1(a0);  // partner's a0
        float s1 = dpp_swap1(a1);  // partner's a1
        float vi = p ? s0 : a0;
        float vf = p ? a0 : s0;
        float vg = p ? s1 : a1;
        float vo = p ? a1 : s1;

        float gi = sigmoidf_(vi);
        float gf = sigmoidf_(vf);
        float gg = tanhf_   (vg);
        float go = sigmoidf_(vo);
        float c2 = gf * c + gi * gg;      // c replicated in both pair lanes
        c = c2;
        float h2n = go * tanhf_(c2);

        half_t* hw = (half_t*)(hh + ((((n & 1) ^ 1)) << 7)); // write other buf
        if (p == 0) {
            hw[u] = (half_t)h2n;
            outs[(size_t)n * H_ + u] = h2n;
        }
        __syncthreads();                 // single barrier per step
        xi0 = nxi0; xi1 = nxi1;
    }
}

// ------------------------- final linear head -------------------------------
__global__ __launch_bounds__(256) void k_final(
    const float* __restrict__ outs, const float* __restrict__ Wl,
    const float* __restrict__ bl, float* __restrict__ y)
{
    const int lane = threadIdx.x & 63;
    const int g = threadIdx.x >> 6;
    const int n = blockIdx.x * 4 + g;
    const float* row = outs + (size_t)n * H_;
    float s = row[lane] * Wl[lane] + row[64 + lane] * Wl[64 + lane]
            + row[128 + lane] * Wl[128 + lane] + row[192 + lane] * Wl[192 + lane];
#pragma unroll
    for (int off = 32; off > 0; off >>= 1) s += __shfl_down(s, off, 64);
    if (lane == 0) y[n] = s + bl[0];
}

// ---------------------------------------------------------------------------
extern "C" void kernel_launch(void* const* d_in, const int* in_sizes, int n_in,
                              void* d_out, int out_size, void* d_ws, size_t ws_size,
                              hipStream_t stream)
{
    const float* tokens = (const float*)d_in[0];
    const int*   lengths= (const int*)  d_in[1];
    const float* Wih_t  = (const float*)d_in[2];
    const float* Whh_t  = (const float*)d_in[3];
    const float* bih_t  = (const float*)d_in[4];
    const float* bhh_t  = (const float*)d_in[5];
    const float* Wih_i  = (const float*)d_in[6];
    const float* Whh_i  = (const float*)d_in[7];
    const float* bih_i  = (const float*)d_in[8];
    const float* bhh_i  = (const float*)d_in[9];
    const float* Wl     = (const float*)d_in[10];
    const float* bl     = (const float*)d_in[11];
    float* out = (float*)d_out;

    char* ws = (char*)d_ws;
    float*  embeds = (float*) (ws);                                // 8 MB
    float*  XI     = (float*) (ws + (size_t)8  * 1024 * 1024);     // 32 MB
    float*  outs   = (float*) (ws + (size_t)40 * 1024 * 1024);     // 8 MB
    float4* WcatT  = (float4*)(ws + (size_t)48 * 1024 * 1024);     // 2 MB
    float4* WiT    = (float4*)(ws + (size_t)50 * 1024 * 1024);     // 1 MB

    (void)hipFuncSetAttribute((const void*)k_seq_lstm,
        hipFuncAttributeMaxDynamicSharedMemorySize, SMEM_SEQ);

    k_transpose_cat<<<512,  256, 0, stream>>>(Wih_t, Whh_t, WcatT);
    k_transpose_i  <<<256,  256, 0, stream>>>(Wih_i, WiT);
    k_token_lstm   <<<512,  256, 0, stream>>>(tokens, lengths, WcatT, bih_t, bhh_t, embeds);
    k_xi           <<<512,  256, 0, stream>>>(embeds, WiT, bih_i, bhh_i, XI);
    k_seq_lstm     <<<1,    512, SMEM_SEQ, stream>>>(XI, Whh_i, outs);
    k_final        <<<2048, 256, 0, stream>>>(outs, Wl, bl, out);
}

// Round 2
// 17612.889 us; speedup vs baseline: 1.0309x; 1.0309x over previous
//
#include <hip/hip_runtime.h>
#include <hip/hip_bf16.h>
#include <hip/hip_fp16.h>

// ---------------------------------------------------------------------------
// ModelInstructionAggregate: token-LSTM (batch 8192, T<=16) -> sequential
// instruction-LSTM (8192 steps, batch 1) -> Linear(256->1).
// Round 5: k_seq_lstm only —
//   (a) REVERT round-4 inline-asm dots (regalloc kept AGPR homes and paid a
//       v_accvgpr_read + tied-move per asm site: VALUBusy went UP).
//   (b) keep round-4 pair-map structure (verified correct): thread 2u owns
//       gate rows {i,g} of unit u, 2u+1 owns {f,o}; DPP lane-swap exchange,
//       c in regs, h f16 double-buffered, ONE barrier/step.
//   (c) register-pressure control: the pre-RA scheduler hoists all h/tail
//       LDS loads (~160 transient regs), pushing peak to ~400 and causing
//       RA to demote the 192 weight-half2 to AGPR (whole-kernel home =>
//       1 v_accvgpr_read per dot). Cap lookahead with sched_barrier(0)
//       every 4 h-float4 (main) / 2 q (tail) / 8 kq (init): peak ~= 253.
//   (d) replace __launch_bounds__ with explicit amdgpu_flat_work_group_size
//       (512,512) + amdgpu_waves_per_eu(2,2): launch_bounds' 2nd arg emits a
//       min-only waves_per_eu(2) that can override the (2,2) pair.
// ---------------------------------------------------------------------------

constexpr int H_ = 256;    // hidden
constexpr int T_ = 16;     // max token steps
constexpr int N_ = 8192;   // instructions
constexpr int BI = 16;     // instructions per block in batched kernels

typedef _Float16 half_t;
typedef half_t half2_t __attribute__((ext_vector_type(2)));

#if __has_builtin(__builtin_amdgcn_fdot2)
#define FDOT2(w, h, acc) __builtin_amdgcn_fdot2((w), (h), (acc), false)
#else
__device__ __forceinline__ float fdot2_emul(half2_t w, half2_t h, float acc) {
    return acc + (float)w.x * (float)h.x + (float)w.y * (float)h.y;
}
#define FDOT2(w, h, acc) fdot2_emul((w), (h), (acc))
#endif

#if __has_builtin(__builtin_amdgcn_sched_barrier)
#define SCHED_FENCE() __builtin_amdgcn_sched_barrier(0)
#else
#define SCHED_FENCE()
#endif

__device__ __forceinline__ float sigmoidf_(float x) {
    return 1.0f / (1.0f + __expf(-x));
}
__device__ __forceinline__ float tanhf_(float x) {
    return 2.0f / (1.0f + __expf(-2.0f * x)) - 1.0f;
}

// lane <-> lane^1 swap via DPP quad_perm {1,0,3,2} (ctrl=0xB1), 1 VALU inst.
__device__ __forceinline__ float dpp_swap1(float x) {
    int xi = __builtin_bit_cast(int, x);
    int r = __builtin_amdgcn_update_dpp(0, xi, 0xB1, 0xF, 0xF, true);
    return __builtin_bit_cast(float, r);
}

// --------------------------- weight transposes -----------------------------
__global__ __launch_bounds__(256) void k_transpose_cat(
    const float* __restrict__ Wih, const float* __restrict__ Whh,
    float4* __restrict__ Wt)
{
    int tid = blockIdx.x * 256 + threadIdx.x;      // 1024 rows * 128 kb
    int kb = tid & 127, row = tid >> 7;
    float4 v = (kb < 64) ? ((const float4*)Wih)[row * 64 + kb]
                         : ((const float4*)Whh)[row * 64 + (kb - 64)];
    Wt[kb * 1024 + row] = v;
}

__global__ __launch_bounds__(256) void k_transpose_i(
    const float* __restrict__ Wsrc, float4* __restrict__ Wt)
{
    int tid = blockIdx.x * 256 + threadIdx.x;      // 1024 rows * 64 kb
    int kb = tid & 63, row = tid >> 6;
    Wt[kb * 1024 + row] = ((const float4*)Wsrc)[row * 64 + kb];
}

// ----------------------- phase 1: batched token LSTM -----------------------
__global__ __launch_bounds__(256, 4) void k_token_lstm(
    const float* __restrict__ tokens, const int* __restrict__ lengths,
    const float4* __restrict__ Wt,   // [128][1024] float4 (x-part then h-part)
    const float* __restrict__ bih, const float* __restrict__ bhh,
    float* __restrict__ embeds)      // [N_][H_]
{
    __shared__ __align__(16) float xs[BI][H_];
    __shared__ __align__(16) float hs[BI][H_];
    __shared__ __align__(16) float cs[BI][H_];
    __shared__ int len[BI];

    const int j = threadIdx.x;
    const int n0 = blockIdx.x * BI;
    if (j < BI) len[j] = lengths[n0 + j];
#pragma unroll
    for (int i = 0; i < BI; ++i) { hs[i][j] = 0.f; cs[i][j] = 0.f; }
    const float b0 = bih[j]       + bhh[j];
    const float b1 = bih[256 + j] + bhh[256 + j];
    const float b2 = bih[512 + j] + bhh[512 + j];
    const float b3 = bih[768 + j] + bhh[768 + j];
    __syncthreads();

    for (int t = 0; t < T_; ++t) {
#pragma unroll
        for (int q = 0; q < 4; ++q) {
            int idx = j + q * 256;
            int i = idx >> 6, e4 = idx & 63;
            ((float4*)xs)[i * 64 + e4] =
                ((const float4*)tokens)[((size_t)(n0 + i) * T_ + t) * 64 + e4];
        }
        __syncthreads();

        float a0[BI], a1[BI], a2[BI], a3[BI];
#pragma unroll
        for (int i = 0; i < BI; ++i) { a0[i] = 0.f; a1[i] = 0.f; a2[i] = 0.f; a3[i] = 0.f; }

        for (int kb = 0; kb < 64; ++kb) {
            float4 w0 = Wt[kb * 1024 + j];
            float4 w1 = Wt[kb * 1024 + 256 + j];
            float4 w2 = Wt[kb * 1024 + 512 + j];
            float4 w3 = Wt[kb * 1024 + 768 + j];
#pragma unroll
            for (int i = 0; i < BI; ++i) {
                float4 x4 = ((const float4*)xs)[i * 64 + kb];
                a0[i] += w0.x * x4.x + w0.y * x4.y + w0.z * x4.z + w0.w * x4.w;
                a1[i] += w1.x * x4.x + w1.y * x4.y + w1.z * x4.z + w1.w * x4.w;
                a2[i] += w2.x * x4.x + w2.y * x4.y + w2.z * x4.z + w2.w * x4.w;
                a3[i] += w3.x * x4.x + w3.y * x4.y + w3.z * x4.z + w3.w * x4.w;
            }
        }
        for (int kb = 0; kb < 64; ++kb) {
            float4 w0 = Wt[(64 + kb) * 1024 + j];
            float4 w1 = Wt[(64 + kb) * 1024 + 256 + j];
            float4 w2 = Wt[(64 + kb) * 1024 + 512 + j];
            float4 w3 = Wt[(64 + kb) * 1024 + 768 + j];
#pragma unroll
            for (int i = 0; i < BI; ++i) {
                float4 h4 = ((const float4*)hs)[i * 64 + kb];
                a0[i] += w0.x * h4.x + w0.y * h4.y + w0.z * h4.z + w0.w * h4.w;
                a1[i] += w1.x * h4.x + w1.y * h4.y + w1.z * h4.z + w1.w * h4.w;
                a2[i] += w2.x * h4.x + w2.y * h4.y + w2.z * h4.z + w2.w * h4.w;
                a3[i] += w3.x * h4.x + w3.y * h4.y + w3.z * h4.z + w3.w * h4.w;
            }
        }
        __syncthreads();

#pragma unroll
        for (int i = 0; i < BI; ++i) {
            if (t < len[i]) {
                float gi = sigmoidf_(a0[i] + b0);
                float gf = sigmoidf_(a1[i] + b1);
                float gg = tanhf_   (a2[i] + b2);
                float go = sigmoidf_(a3[i] + b3);
                float c2 = gf * cs[i][j] + gi * gg;
                cs[i][j] = c2;
                hs[i][j] = go * tanhf_(c2);
            }
        }
    }
#pragma unroll
    for (int i = 0; i < BI; ++i)
        embeds[(size_t)(n0 + i) * H_ + j] = hs[i][j];
}

// --------------------- phase 2a: XI = embeds @ Wih_i^T + b ------------------
__global__ __launch_bounds__(256, 4) void k_xi(
    const float* __restrict__ embeds, const float4* __restrict__ WiT, // [64][1024]
    const float* __restrict__ bih, const float* __restrict__ bhh,
    float* __restrict__ XI)          // [N_][1024]
{
    __shared__ __align__(16) float xs[BI][H_];
    const int j = threadIdx.x;
    const int n0 = blockIdx.x * BI;
#pragma unroll
    for (int q = 0; q < 4; ++q) {
        int idx = j + q * 256;
        int i = idx >> 6, e4 = idx & 63;
        ((float4*)xs)[i * 64 + e4] = ((const float4*)embeds)[(size_t)(n0 + i) * 64 + e4];
    }
    const float b0 = bih[j]       + bhh[j];
    const float b1 = bih[256 + j] + bhh[256 + j];
    const float b2 = bih[512 + j] + bhh[512 + j];
    const float b3 = bih[768 + j] + bhh[768 + j];
    __syncthreads();

    float a0[BI], a1[BI], a2[BI], a3[BI];
#pragma unroll
    for (int i = 0; i < BI; ++i) { a0[i] = 0.f; a1[i] = 0.f; a2[i] = 0.f; a3[i] = 0.f; }

    for (int kb = 0; kb < 64; ++kb) {
        float4 w0 = WiT[kb * 1024 + j];
        float4 w1 = WiT[kb * 1024 + 256 + j];
        float4 w2 = WiT[kb * 1024 + 512 + j];
        float4 w3 = WiT[kb * 1024 + 768 + j];
#pragma unroll
        for (int i = 0; i < BI; ++i) {
            float4 x4 = ((const float4*)xs)[i * 64 + kb];
            a0[i] += w0.x * x4.x + w0.y * x4.y + w0.z * x4.z + w0.w * x4.w;
            a1[i] += w1.x * x4.x + w1.y * x4.y + w1.z * x4.z + w1.w * x4.w;
            a2[i] += w2.x * x4.x + w2.y * x4.y + w2.z * x4.z + w2.w * x4.w;
            a3[i] += w3.x * x4.x + w3.y * x4.y + w3.z * x4.z + w3.w * x4.w;
        }
    }
#pragma unroll
    for (int i = 0; i < BI; ++i) {
        size_t base = (size_t)(n0 + i) * 1024;
        XI[base + j]       = a0[i] + b0;
        XI[base + 256 + j] = a1[i] + b1;
        XI[base + 512 + j] = a2[i] + b2;
        XI[base + 768 + j] = a3[i] + b3;
    }
}

// ----------------- phase 2b: sequential instruction LSTM -------------------
// Single workgroup, 512 threads. Thread pair (2u, 2u+1) owns h-unit u:
//   lane 2u   computes gate rows r0=u       (i) and r1=512+u (g)
//   lane 2u+1 computes gate rows r0=256+u   (f) and r1=768+u (o)
// k 0..191 in arch VGPRs (96 half2/row), k 192..255 in LDS (uint4).
// Gate exchange = 2 DPP lane swaps; c in regs; h f16 double-buffered in LDS;
// ONE barrier per step. sched_barrier(0) groups cap in-flight LDS loads so
// peak arch pressure stays <= 256 and RA keeps the weights out of AGPRs.
constexpr int SMEM_SEQ = 1024 /*hh dbuf*/ + 8 * 1024 * 16 /*wt4*/; // 132096 B

__global__
__attribute__((amdgpu_flat_work_group_size(512, 512)))
__attribute__((amdgpu_waves_per_eu(2, 2)))
void k_seq_lstm(
    const float* __restrict__ XI,    // [N_][1024]
    const float* __restrict__ Whh,   // [1024][256]
    float* __restrict__ outs)        // [N_][H_]
{
    extern __shared__ char smem[];
    half2_t* hh  = (half2_t*)smem;               // [2][128] half2 (h dbuf)
    uint4*   wt4 = (uint4*)(smem + 1024);        // [8][1024] k-tail

    const int j = threadIdx.x;
    const int p = j & 1;                 // 0 -> (i,g) rows, 1 -> (f,o) rows
    const int u = j >> 1;                // h-unit 0..255
    const int r0 = p * 256 + u;          // row in [0,512)
    const int r1 = 512 + p * 256 + u;    // row in [512,1024)

    half2_t wa[96], wb[96];
    {
        const float4* w0v = (const float4*)(Whh + (size_t)r0 * H_);
        const float4* w1v = (const float4*)(Whh + (size_t)r1 * H_);
#pragma unroll
        for (int kg = 0; kg < 6; ++kg) {         // 6 groups of 8 float4-pairs
#pragma unroll
            for (int kq = kg * 8; kq < kg * 8 + 8; ++kq) {
                float4 v0 = w0v[kq], v1 = w1v[kq];
                wa[2 * kq]     = half2_t{(half_t)v0.x, (half_t)v0.y};
                wa[2 * kq + 1] = half2_t{(half_t)v0.z, (half_t)v0.w};
                wb[2 * kq]     = half2_t{(half_t)v1.x, (half_t)v1.y};
                wb[2 * kq + 1] = half2_t{(half_t)v1.z, (half_t)v1.w};
            }
            SCHED_FENCE();                       // cap init-phase peak pressure
        }
#pragma unroll
        for (int q = 0; q < 8; ++q) {            // k 192..255 -> LDS uint4
            float4 vA = w0v[48 + 2 * q], vB = w0v[48 + 2 * q + 1];
            uint4 u0;
            u0.x = __builtin_bit_cast(unsigned, half2_t{(half_t)vA.x, (half_t)vA.y});
            u0.y = __builtin_bit_cast(unsigned, half2_t{(half_t)vA.z, (half_t)vA.w});
            u0.z = __builtin_bit_cast(unsigned, half2_t{(half_t)vB.x, (half_t)vB.y});
            u0.w = __builtin_bit_cast(unsigned, half2_t{(half_t)vB.z, (half_t)vB.w});
            wt4[q * 1024 + j] = u0;
            float4 vC = w1v[48 + 2 * q], vD = w1v[48 + 2 * q + 1];
            uint4 u1;
            u1.x = __builtin_bit_cast(unsigned, half2_t{(half_t)vC.x, (half_t)vC.y});
            u1.y = __builtin_bit_cast(unsigned, half2_t{(half_t)vC.z, (half_t)vC.w});
            u1.z = __builtin_bit_cast(unsigned, half2_t{(half_t)vD.x, (half_t)vD.y});
            u1.w = __builtin_bit_cast(unsigned, half2_t{(half_t)vD.z, (half_t)vD.w});
            wt4[q * 1024 + 512 + j] = u1;
            if ((q & 1) != 0) SCHED_FENCE();
        }
    }
    if (j < 128) hh[j] = half2_t{(half_t)0.f, (half_t)0.f};  // h buffer 0 = 0
    __syncthreads();

    float c = 0.f;
    float xi0 = XI[r0], xi1 = XI[r1];
    for (int n = 0; n < N_; ++n) {
        // prefetch next step's XI (last iter re-reads current row; unused)
        const int nn = (n + 1 < N_) ? n + 1 : n;
        const float* pX = XI + (size_t)nn * 1024;
        float nxi0 = pX[r0], nxi1 = pX[r1];

        const float4* hv = (const float4*)(hh + ((n & 1) << 7));
        float acc0 = xi0, acc0b = 0.f, acc1 = xi1, acc1b = 0.f;
#pragma unroll
        for (int g = 0; g < 6; ++g) {          // k 0..191, 4 float4 per group
#pragma unroll
            for (int m = 0; m < 4; ++m) {
                int kk4 = 4 * g + m;
                float4 h4 = hv[kk4];           // wave-uniform LDS broadcast
                half2_t h0 = __builtin_bit_cast(half2_t, h4.x);
                half2_t h1 = __builtin_bit_cast(half2_t, h4.y);
                half2_t h2 = __builtin_bit_cast(half2_t, h4.z);
                half2_t h3 = __builtin_bit_cast(half2_t, h4.w);
                acc0  = FDOT2(wa[4 * kk4 + 0], h0, acc0);
                acc0b = FDOT2(wa[4 * kk4 + 1], h1, acc0b);
                acc0  = FDOT2(wa[4 * kk4 + 2], h2, acc0);
                acc0b = FDOT2(wa[4 * kk4 + 3], h3, acc0b);
                acc1  = FDOT2(wb[4 * kk4 + 0], h0, acc1);
                acc1b = FDOT2(wb[4 * kk4 + 1], h1, acc1b);
                acc1  = FDOT2(wb[4 * kk4 + 2], h2, acc1);
                acc1b = FDOT2(wb[4 * kk4 + 3], h3, acc1b);
            }
            SCHED_FENCE();                     // cap in-flight h-loads (<=16 regs)
        }
#pragma unroll
        for (int qg = 0; qg < 4; ++qg) {       // k 192..255 (LDS weights)
#pragma unroll
            for (int qq = 0; qq < 2; ++qq) {
                int q = qg * 2 + qq;
                uint4 u0 = wt4[q * 1024 + j];
                uint4 u1 = wt4[q * 1024 + 512 + j];
                float4 h4 = hv[24 + q];
                half2_t h0 = __builtin_bit_cast(half2_t, h4.x);
                half2_t h1 = __builtin_bit_cast(half2_t, h4.y);
                half2_t h2 = __builtin_bit_cast(half2_t, h4.z);
                half2_t h3 = __builtin_bit_cast(half2_t, h4.w);
                acc0  = FDOT2(__builtin_bit_cast(half2_t, u0.x), h0, acc0);
                acc0b = FDOT2(__builtin_bit_cast(half2_t, u0.y), h1, acc0b);
                acc0  = FDOT2(__builtin_bit_cast(half2_t, u0.z), h2, acc0);
                acc0b = FDOT2(__builtin_bit_cast(half2_t, u0.w), h3, acc0b);
                acc1  = FDOT2(__builtin_bit_cast(half2_t, u1.x), h0, acc1);
                acc1b = FDOT2(__builtin_bit_cast(half2_t, u1.y), h1, acc1b);
                acc1  = FDOT2(__builtin_bit_cast(half2_t, u1.z), h2, acc1);
                acc1b = FDOT2(__builtin_bit_cast(half2_t, u1.w), h3, acc1b);
            }
            SCHED_FENCE();                     // cap in-flight tail loads (<=16 regs)
        }
        float a0 = acc0 + acc0b;   // p=0: i-gate,  p=1: f-gate
        float a1 = acc1 + acc1b;   // p=0: g-gate,  p=1: o-gate
        float s0 = dpp_swap1(a0);  // partner's a0
        float s1 = dpp_swap1(a1);  // partner's a1
        float vi = p ? s0 : a0;
        float vf = p ? a0 : s0;
        float vg = p ? s1 : a1;
        float vo = p ? a1 : s1;

        float gi = sigmoidf_(vi);
        float gf = sigmoidf_(vf);
        float gg = tanhf_   (vg);
        float go = sigmoidf_(vo);
        float c2 = gf * c + gi * gg;      // c replicated in both pair lanes
        c = c2;
        float h2n = go * tanhf_(c2);

        half_t* hw = (half_t*)(hh + ((((n & 1) ^ 1)) << 7)); // write other buf
        if (p == 0) {
            hw[u] = (half_t)h2n;
            outs[(size_t)n * H_ + u] = h2n;
        }
        __syncthreads();                 // single barrier per step
        xi0 = nxi0; xi1 = nxi1;
    }
}

// ------------------------- final linear head -------------------------------
__global__ __launch_bounds__(256) void k_final(
    const float* __restrict__ outs, const float* __restrict__ Wl,
    const float* __restrict__ bl, float* __restrict__ y)
{
    const int lane = threadIdx.x & 63;
    const int g = threadIdx.x >> 6;
    const int n = blockIdx.x * 4 + g;
    const float* row = outs + (size_t)n * H_;
    float s = row[lane] * Wl[lane] + row[64 + lane] * Wl[64 + lane]
            + row[128 + lane] * Wl[128 + lane] + row[192 + lane] * Wl[192 + lane];
#pragma unroll
    for (int off = 32; off > 0; off >>= 1) s += __shfl_down(s, off, 64);
    if (lane == 0) y[n] = s + bl[0];
}

// ---------------------------------------------------------------------------
extern "C" void kernel_launch(void* const* d_in, const int* in_sizes, int n_in,
                              void* d_out, int out_size, void* d_ws, size_t ws_size,
                              hipStream_t stream)
{
    const float* tokens = (const float*)d_in[0];
    const int*   lengths= (const int*)  d_in[1];
    const float* Wih_t  = (const float*)d_in[2];
    const float* Whh_t  = (const float*)d_in[3];
    const float* bih_t  = (const float*)d_in[4];
    const float* bhh_t  = (const float*)d_in[5];
    const float* Wih_i  = (const float*)d_in[6];
    const float* Whh_i  = (const float*)d_in[7];
    const float* bih_i  = (const float*)d_in[8];
    const float* bhh_i  = (const float*)d_in[9];
    const float* Wl     = (const float*)d_in[10];
    const float* bl     = (const float*)d_in[11];
    float* out = (float*)d_out;

    char* ws = (char*)d_ws;
    float*  embeds = (float*) (ws);                                // 8 MB
    float*  XI     = (float*) (ws + (size_t)8  * 1024 * 1024);     // 32 MB
    float*  outs   = (float*) (ws + (size_t)40 * 1024 * 1024);     // 8 MB
    float4* WcatT  = (float4*)(ws + (size_t)48 * 1024 * 1024);     // 2 MB
    float4* WiT    = (float4*)(ws + (size_t)50 * 1024 * 1024);     // 1 MB

    (void)hipFuncSetAttribute((const void*)k_seq_lstm,
        hipFuncAttributeMaxDynamicSharedMemorySize, SMEM_SEQ);

    k_transpose_cat<<<512,  256, 0, stream>>>(Wih_t, Whh_t, WcatT);
    k_transpose_i  <<<256,  256, 0, stream>>>(Wih_i, WiT);
    k_token_lstm   <<<512,  256, 0, stream>>>(tokens, lengths, WcatT, bih_t, bhh_t, embeds);
    k_xi           <<<512,  256, 0, stream>>>(embeds, WiT, bih_i, bhh_i, XI);
    k_seq_lstm     <<<1,    512, SMEM_SEQ, stream>>>(XI, Whh_i, outs);
    k_final        <<<2048, 256, 0, stream>>>(outs, Wl, bl, out);
}